// Round 1
// 412.649 us; speedup vs baseline: 1.0264x; 1.0264x over previous
//
#include <hip/hip_runtime.h>

// nnmodel_35708358099045 R4: latency/occupancy attack. R3 math kept verbatim.
// Evidence: 179 us/dispatch vs ~67 us memory floor AND ~70 us VALU floor;
// VALUBusy 35% (sum-of-4-SIMDs ~ 9%/SIMD), Occupancy 10.65% ~= 3.4 waves/CU
// resident vs 12 theoretical -> latency-bound via low residency + 4 serialized
// load->barrier phases (each barrier drains vmcnt(0)).
// Changes:
// - TPB 64 -> 256: 4 INDEPENDENT waves per block, per-wave-private LDS
//   regions (64 rows x 11 float4 each, 45056 B total -> 3 blocks/CU = 12
//   waves/CU). Sidesteps any per-CU workgroup-slot cap on tiny 1-wave blocks.
// - NO __syncthreads anywhere: cross-lane transpose is same-wave only; the
//   DS pipe is in-order per wave, so ds_write -> s_waitcnt lgkmcnt(0) ->
//   ds_read is sufficient. sched_barrier(0) after the inline waitcnt stops
//   hipcc hoisting (known hazard). No vmcnt(0) barrier drains remain.
// - z bypasses LDS entirely: each lane loads its own 320 B z row as 20
//   global_load_dwordx4 issued up front (max loads-in-flight), consumed
//   half (nodes 0-4 -> rA) then half (nodes 5-9 -> rB). Removes 2 stage
//   phases and 40 LDS ops/thread.

#define HN 10
#define ND 40
#define HF 8
#define TPB 256
#define WLEN 64
#define ROW4 11   // padded per-wave LDS row stride in float4 (odd -> b128 conflict-free)

__global__ __launch_bounds__(TPB) void gnn_kernel(
    const float* __restrict__ x,          // [B, 40]
    const float* __restrict__ z,          // [B, 10, 8]
    const float* __restrict__ y,          // [B, 40]
    const float* __restrict__ enc_rel_w,  // [8, 1]
    const float* __restrict__ enc_rel_b,  // [8]
    const float* __restrict__ enc_root_w, // [8, 8]
    const float* __restrict__ pred_rel_w, // [8, 8]
    const float* __restrict__ pred_rel_b, // [8]
    const float* __restrict__ pred_root_w,// [8, 8]
    const float* __restrict__ dec_rel_w,  // [1, 8]
    const float* __restrict__ dec_rel_b,  // [1]
    const float* __restrict__ dec_root_w, // [1, 1]
    float* __restrict__ out,              // [B, 40]
    int B)
{
    __shared__ float4 lds4[TPB * ROW4];   // 45056 B, 4 private 64x11 regions
    const int t    = threadIdx.x;
    const int lane = t & 63;
    const int wv   = t >> 6;
    const long long wbase = (long long)blockIdx.x * TPB + wv * WLEN; // wave's elem base
    float4* wl = lds4 + wv * (WLEN * ROW4);                          // wave's LDS region

    const float w = 0.8948393168143698f;  // exp(-(1/3)^2) as fp32

    // ---------- phase X: stage x tile (coalesced global, padded LDS) ----------
    const float4* xg = (const float4*)(x + wbase * ND);
    #pragma unroll
    for (int k = 0; k < 10; ++k) {
        int i = lane + WLEN * k;          // 0..639 within wave tile
        int e = i / 10, q = i - e * 10;   // elem-in-wave, float4-in-row
        wl[e * ROW4 + q] = xg[i];
    }
    // same-wave transpose: wait own wave's ds_writes, then cross-lane read.
    asm volatile("s_waitcnt lgkmcnt(0)" ::: "memory");
    __builtin_amdgcn_sched_barrier(0);

    float agg[HN];
    {
        float xv[ND];
        #pragma unroll
        for (int k = 0; k < 10; ++k) {
            float4 v = wl[lane * ROW4 + k];   // 3*lane mod 8 permutation -> conflict-free
            xv[4*k+0] = v.x; xv[4*k+1] = v.y; xv[4*k+2] = v.z; xv[4*k+3] = v.w;
        }
        agg[0] = xv[37] + xv[38] + xv[39] + xv[0] + xv[1] + xv[2];
        #pragma unroll
        for (int j = 1; j < HN; ++j)
            agg[j] = xv[4*j-3] + xv[4*j-2] + xv[4*j-1] + xv[4*j] + xv[4*j+1] + xv[4*j+2];
    }

    // ---------- z: direct per-lane loads, no LDS, all in flight ----------
    const float4* zrow = (const float4*)(z + (wbase + lane) * (HN * HF)); // own 320 B
    float4 zA[10], zB[10];
    #pragma unroll
    for (int k = 0; k < 10; ++k) zA[k] = zrow[k];        // nodes 0..4
    #pragma unroll
    for (int k = 0; k < 10; ++k) zB[k] = zrow[10 + k];   // nodes 5..9

    // encoder GraphConv row j from two z float4s (registers only)
    auto enc_row = [&](float4 v0, float4 v1, int j, float (&r)[HF]) {
        float zr[HF] = {v0.x, v0.y, v0.z, v0.w, v1.x, v1.y, v1.z, v1.w};
        #pragma unroll
        for (int f = 0; f < HF; ++f) {
            float acc = agg[j] * enc_rel_w[f] + enc_rel_b[f];
            #pragma unroll
            for (int g = 0; g < HF; ++g)
                acc += zr[g] * enc_root_w[f * HF + g];
            r[f] = fmaxf(acc, 0.0f);
        }
    };

    // predictor + decoder row-dot: s2 for center row rc with neighbors rm, rp
    auto emit = [&](const float (&rm)[HF], const float (&rc)[HF],
                    const float (&rp)[HF]) -> float {
        float a2[HF];
        #pragma unroll
        for (int f = 0; f < HF; ++f)
            a2[f] = rc[f] + w * (rm[f] + rp[f]);
        float s = 0.0f;
        #pragma unroll
        for (int f = 0; f < HF; ++f) {
            float acc = pred_rel_b[f];
            #pragma unroll
            for (int g = 0; g < HF; ++g)
                acc += a2[g] * pred_rel_w[f * HF + g];
            #pragma unroll
            for (int g = 0; g < HF; ++g)
                acc += rc[g] * pred_root_w[f * HF + g];
            s += fmaxf(acc, 0.0f) * dec_rel_w[f];
        }
        return s;
    };

    float rA[5][HF], rB[5][HF];
    #pragma unroll
    for (int jj = 0; jj < 5; ++jj) enc_row(zA[2*jj], zA[2*jj+1], jj, rA[jj]);
    #pragma unroll
    for (int jj = 0; jj < 5; ++jj) enc_row(zB[2*jj], zB[2*jj+1], 5 + jj, rB[jj]);

    float s2[HN];
    s2[1] = emit(rA[0], rA[1], rA[2]);
    s2[2] = emit(rA[1], rA[2], rA[3]);
    s2[3] = emit(rA[2], rA[3], rA[4]);
    s2[4] = emit(rA[3], rA[4], rB[0]);
    s2[5] = emit(rA[4], rB[0], rB[1]);
    s2[6] = emit(rB[0], rB[1], rB[2]);
    s2[7] = emit(rB[1], rB[2], rB[3]);
    s2[8] = emit(rB[2], rB[3], rB[4]);
    s2[9] = emit(rB[3], rB[4], rA[0]);
    s2[0] = emit(rB[4], rA[0], rA[1]);

    // ---------- phase O: stage out partials as float4 (same padded layout) ----
    const float drb   = dec_rel_b[0];
    const float droot = dec_root_w[0];
    #pragma unroll
    for (int k = 0; k < 10; ++k) {
        const int k1 = (k + 1) % HN;
        const float pair = s2[k] + s2[k1] + drb;
        float4 vo;
        vo.x = s2[k] + drb;
        vo.y = pair;
        vo.z = pair;
        vo.w = s2[k1] + drb;
        wl[lane * ROW4 + k] = vo;         // b128, stride 11 -> conflict-free
    }
    asm volatile("s_waitcnt lgkmcnt(0)" ::: "memory");
    __builtin_amdgcn_sched_barrier(0);

    // drain: out = partial + y * droot, fully coalesced global float4
    const float4* yg = (const float4*)(y + wbase * ND);
    float4* og = (float4*)(out + wbase * ND);
    #pragma unroll
    for (int k = 0; k < 10; ++k) {
        int i = lane + WLEN * k;
        int e = i / 10, q = i - e * 10;
        float4 p = wl[e * ROW4 + q];      // near-sequential addrs -> conflict-free
        float4 vy = yg[i];
        p.x += vy.x * droot;
        p.y += vy.y * droot;
        p.z += vy.z * droot;
        p.w += vy.w * droot;
        og[i] = p;
    }
}

extern "C" void kernel_launch(void* const* d_in, const int* in_sizes, int n_in,
                              void* d_out, int out_size, void* d_ws, size_t ws_size,
                              hipStream_t stream) {
    const float* x          = (const float*)d_in[0];
    const float* z          = (const float*)d_in[1];
    const float* y          = (const float*)d_in[2];
    const float* enc_rel_w  = (const float*)d_in[3];
    const float* enc_rel_b  = (const float*)d_in[4];
    const float* enc_root_w = (const float*)d_in[5];
    const float* pred_rel_w = (const float*)d_in[6];
    const float* pred_rel_b = (const float*)d_in[7];
    const float* pred_root_w= (const float*)d_in[8];
    const float* dec_rel_w  = (const float*)d_in[9];
    const float* dec_rel_b  = (const float*)d_in[10];
    const float* dec_root_w = (const float*)d_in[11];
    float* out = (float*)d_out;

    const int B = in_sizes[0] / ND;       // 524288, divisible by TPB
    const int blocks = B / TPB;
    gnn_kernel<<<blocks, TPB, 0, stream>>>(
        x, z, y, enc_rel_w, enc_rel_b, enc_root_w,
        pred_rel_w, pred_rel_b, pred_root_w,
        dec_rel_w, dec_rel_b, dec_root_w, out, B);
}